// Round 1
// baseline (812.593 us; speedup 1.0000x reference)
//
#include <hip/hip_runtime.h>

#define N_NODES 100000
#define N_EDGES 1600000

typedef __bf16 bf16x8 __attribute__((ext_vector_type(8)));
typedef float f32x4 __attribute__((ext_vector_type(4)));

__device__ __forceinline__ __bf16 f2bf(float f) { return (__bf16)f; }

__device__ __forceinline__ bf16x8 cvt8(float4 a, float4 b) {
    bf16x8 r;
    r[0] = f2bf(a.x); r[1] = f2bf(a.y); r[2] = f2bf(a.z); r[3] = f2bf(a.w);
    r[4] = f2bf(b.x); r[5] = f2bf(b.y); r[6] = f2bf(b.z); r[7] = f2bf(b.w);
    return r;
}

// ---------------------------------------------------------------------------
// K1: node GEMMs. f_ni = nfeats@W_ni, f_nj = nfeats@W_nj, h_src = nfeats@W_src + b_src
// Block = 192 threads = 3 waves; wave w handles matrix w for the same 16-node chunk
// (shared nfeats rows hit L1). W held in registers as MFMA B-frags (64 VGPRs).
// MFMA A layout: A[m=lane&15][k=(lane>>4)*8+j]; C layout: col=lane&15, row=(lane>>4)*4+reg.
// ---------------------------------------------------------------------------
__global__ __launch_bounds__(192) void k_node(
    const float* __restrict__ nfeats,
    const float* __restrict__ Wni, const float* __restrict__ Wnj,
    const float* __restrict__ Wsrc, const float* __restrict__ bsrc,
    float* __restrict__ fni, float* __restrict__ fnj, float* __restrict__ hsrc) {
    const int wid  = threadIdx.x >> 6;
    const int lane = threadIdx.x & 63;
    const int quad = lane >> 4, n = lane & 15;

    const float* W  = (wid == 0) ? Wni : (wid == 1) ? Wnj : Wsrc;
    float*       out = (wid == 0) ? fni : (wid == 1) ? fnj : hsrc;

    // B-frags: Bf[t][kc] holds W[k = kc*32 + quad*8 + j][t*16 + n]
    bf16x8 Bf[4][4];
#pragma unroll
    for (int t = 0; t < 4; ++t)
#pragma unroll
        for (int kc = 0; kc < 4; ++kc)
#pragma unroll
            for (int j = 0; j < 8; ++j) {
                int k = kc * 32 + quad * 8 + j;
                Bf[t][kc][j] = f2bf(W[k * 64 + t * 16 + n]);
            }
    float bs[4];
#pragma unroll
    for (int t = 0; t < 4; ++t) bs[t] = (wid == 2) ? bsrc[t * 16 + n] : 0.0f;

    for (int chunk = blockIdx.x; chunk < N_NODES / 16; chunk += gridDim.x) {
        const int n0 = chunk * 16;
        const float* ap = nfeats + (n0 + n) * 128 + quad * 8;
        bf16x8 Af[4];
#pragma unroll
        for (int kc = 0; kc < 4; ++kc) {
            float4 a0 = *(const float4*)(ap + kc * 32);
            float4 a1 = *(const float4*)(ap + kc * 32 + 4);
            Af[kc] = cvt8(a0, a1);
        }
#pragma unroll
        for (int t = 0; t < 4; ++t) {
            f32x4 acc = {0.f, 0.f, 0.f, 0.f};
#pragma unroll
            for (int kc = 0; kc < 4; ++kc)
                acc = __builtin_amdgcn_mfma_f32_16x16x32_bf16(Af[kc], Bf[t][kc], acc, 0, 0, 0);
#pragma unroll
            for (int reg = 0; reg < 4; ++reg) {
                int row = quad * 4 + reg;
                out[(n0 + row) * 64 + t * 16 + n] = acc[reg] + bs[t];
            }
        }
    }
}

// ---------------------------------------------------------------------------
// K2: fused edge pass 1. Per 16-edge chunk per wave:
//   f_fij = efeats@W_fij via MFMA (W_fij B-frags in 32 VGPRs, A direct from global),
//   f_out = leaky(f_fij + f_ni[src] + f_nj[dst] + bias_e)  (line-coalesced gathers),
//   res_e = 0.25 * sum_h f_out   (pure in-register: tile t == head t, col == d),
//   logits via wave-private LDS round-trip (C-layout -> [edge][64] rows), exp,
//   atomicAdd into z[dst][h].  Softmax max-shift elided (|e| < ~3, exact math).
// ---------------------------------------------------------------------------
__global__ __launch_bounds__(256) void k_edge1(
    const float* __restrict__ efeats,
    const int* __restrict__ src, const int* __restrict__ dst,
    const float* __restrict__ Wf, const float* __restrict__ biasE,
    const float* __restrict__ attn,
    const float* __restrict__ fni, const float* __restrict__ fnj,
    float* __restrict__ rese, float* __restrict__ exw, float* __restrict__ z) {
    __shared__ float shF[4][16][68];  // per-wave private [16 edges][64+pad]
    const int wid  = threadIdx.x >> 6;
    const int lane = threadIdx.x & 63;
    const int quad = lane >> 4, dcol = lane & 15;

    bf16x8 Bf[4][2];
#pragma unroll
    for (int t = 0; t < 4; ++t)
#pragma unroll
        for (int q = 0; q < 2; ++q)
#pragma unroll
            for (int j = 0; j < 8; ++j) {
                int k = q * 32 + quad * 8 + j;
                Bf[t][q][j] = f2bf(Wf[k * 64 + t * 16 + dcol]);
            }
    float bias_r[4];
#pragma unroll
    for (int h = 0; h < 4; ++h) bias_r[h] = biasE[h * 16 + dcol];

    const int h4 = lane & 3, el = lane >> 2;  // logit-stage roles
    float atr[16];
#pragma unroll
    for (int i = 0; i < 16; ++i) atr[i] = attn[h4 * 16 + i];

    const int nchunk = N_EDGES / 16;
    const int wgid = blockIdx.x * 4 + wid;
    const int nw   = gridDim.x * 4;
    for (int chunk = wgid; chunk < nchunk; chunk += nw) {
        const int e0 = chunk * 16;
        const float* ap = efeats + (e0 + dcol) * 64 + quad * 8;  // A row m = lane&15
        bf16x8 af0 = cvt8(*(const float4*)ap, *(const float4*)(ap + 4));
        bf16x8 af1 = cvt8(*(const float4*)(ap + 32), *(const float4*)(ap + 36));
        f32x4 acc[4];
#pragma unroll
        for (int t = 0; t < 4; ++t) {
            f32x4 c0 = {0.f, 0.f, 0.f, 0.f};
            c0     = __builtin_amdgcn_mfma_f32_16x16x32_bf16(af0, Bf[t][0], c0, 0, 0, 0);
            acc[t] = __builtin_amdgcn_mfma_f32_16x16x32_bf16(af1, Bf[t][1], c0, 0, 0, 0);
        }
#pragma unroll
        for (int reg = 0; reg < 4; ++reg) {
            const int row = quad * 4 + reg;
            const int er  = e0 + row;
            const int s = src[er], dd = dst[er];
            const float* pni = fni + s * 64 + dcol;
            const float* pnj = fnj + dd * 64 + dcol;
            float re = 0.f;
#pragma unroll
            for (int h = 0; h < 4; ++h) {
                float v = acc[h][reg] + pni[h * 16] + pnj[h * 16] + bias_r[h];
                v = (v > 0.f) ? v : 0.01f * v;
                re += v;
                shF[wid][row][h * 16 + dcol] = v;
            }
            rese[er * 16 + dcol] = 0.25f * re;
        }
        // logits: lane covers (edge el, head h4); wave-private LDS, no barrier needed
        const float* pf = &shF[wid][el][h4 * 16];
        float4 b0 = *(const float4*)pf;
        float4 b1 = *(const float4*)(pf + 4);
        float4 b2 = *(const float4*)(pf + 8);
        float4 b3 = *(const float4*)(pf + 12);
        float eh = b0.x * atr[0]  + b0.y * atr[1]  + b0.z * atr[2]  + b0.w * atr[3]
                 + b1.x * atr[4]  + b1.y * atr[5]  + b1.z * atr[6]  + b1.w * atr[7]
                 + b2.x * atr[8]  + b2.y * atr[9]  + b2.z * atr[10] + b2.w * atr[11]
                 + b3.x * atr[12] + b3.y * atr[13] + b3.z * atr[14] + b3.w * atr[15];
        float exv = __expf(eh);
        exw[e0 * 4 + lane] = exv;  // (e0+el)*4 + h4 == e0*4 + lane
        const int de = dst[e0 + el];
        atomicAdd(&z[de * 4 + h4], exv);
    }
}

// ---------------------------------------------------------------------------
// K3: edge pass 2. a = ex / z[dst]; res_n[dst] += 0.25 * sum_h a_h * h_src[src][h][d]
// One thread per (edge, d); one fp32 atomic per lane (line-coalesced per edge).
// ---------------------------------------------------------------------------
__global__ __launch_bounds__(256) void k_edge2(
    const float* __restrict__ exw, const float* __restrict__ z,
    const int* __restrict__ src, const int* __restrict__ dst,
    const float* __restrict__ hsrc, float* __restrict__ resn) {
    const long total  = (long)N_EDGES * 16;
    const long stride = (long)gridDim.x * blockDim.x;
    for (long i = (long)blockIdx.x * blockDim.x + threadIdx.x; i < total; i += stride) {
        const int e = (int)(i >> 4);
        const int d = (int)(i & 15);
        const float4 exv = *(const float4*)(exw + e * 4);
        const int dn = dst[e], sn = src[e];
        const float4 zv = *(const float4*)(z + dn * 4);
        const float* hp = hsrc + sn * 64 + d;
        float v = exv.x * __builtin_amdgcn_rcpf(zv.x) * hp[0]
                + exv.y * __builtin_amdgcn_rcpf(zv.y) * hp[16]
                + exv.z * __builtin_amdgcn_rcpf(zv.z) * hp[32]
                + exv.w * __builtin_amdgcn_rcpf(zv.w) * hp[48];
        atomicAdd(resn + dn * 16 + d, 0.25f * v);
    }
}

extern "C" void kernel_launch(void* const* d_in, const int* in_sizes, int n_in,
                              void* d_out, int out_size, void* d_ws, size_t ws_size,
                              hipStream_t stream) {
    const float* nfeats = (const float*)d_in[0];
    const float* efeats = (const float*)d_in[1];
    const int*   src    = (const int*)d_in[2];
    const int*   dst    = (const int*)d_in[3];
    const float* W_ni   = (const float*)d_in[4];
    const float* W_nj   = (const float*)d_in[5];
    const float* W_fij  = (const float*)d_in[6];
    const float* W_src  = (const float*)d_in[7];
    const float* b_src  = (const float*)d_in[8];
    const float* attn   = (const float*)d_in[9];
    const float* bias_e = (const float*)d_in[10];

    float* resn = (float*)d_out;                       // [N, 16]
    float* rese = resn + (size_t)N_NODES * 16;         // [E, 16]

    float* ws   = (float*)d_ws;                        // needs 104 MB
    float* fni  = ws;                                  // [N, 64]
    float* fnj  = fni  + (size_t)N_NODES * 64;         // [N, 64]
    float* hsrc = fnj  + (size_t)N_NODES * 64;         // [N, 64]
    float* exw  = hsrc + (size_t)N_NODES * 64;         // [E, 4]
    float* z    = exw  + (size_t)N_EDGES * 4;          // [N, 4]

    hipMemsetAsync(z, 0, (size_t)N_NODES * 4 * sizeof(float), stream);
    hipMemsetAsync(resn, 0, (size_t)N_NODES * 16 * sizeof(float), stream);

    k_node<<<1024, 192, 0, stream>>>(nfeats, W_ni, W_nj, W_src, b_src, fni, fnj, hsrc);
    k_edge1<<<4096, 256, 0, stream>>>(efeats, src, dst, W_fij, bias_e, attn,
                                      fni, fnj, rese, exw, z);
    k_edge2<<<8192, 256, 0, stream>>>(exw, z, src, dst, hsrc, resn);
}